// Round 12
// baseline (300.001 us; speedup 1.0000x reference)
//
#include <hip/hip_runtime.h>
#include <hip/hip_bf16.h>
#include <math.h>

#define N_NODES_C 100000
#define N_EDGES_C 1600000
#define N_GRAPHS_C 512
#define BSHIFT 10
#define BSIZE (1 << BSHIFT)
#define NBUCK ((N_NODES_C + BSIZE - 1) >> BSHIFT)   // 98
#define CHUNK_A 8192

typedef unsigned int  uint_t;
typedef unsigned short ushort_t;

__device__ __forceinline__ float elu_f(float x) { return x > 0.f ? x : expm1f(x); }

// bf16 helpers (RNE pack, shift unpack). Finite values only.
__device__ __forceinline__ ushort_t f2bf(float f) {
    uint_t u = __float_as_uint(f);
    u += 0x7FFFu + ((u >> 16) & 1u);
    return (ushort_t)(u >> 16);
}
__device__ __forceinline__ uint_t pack2bf(float lo, float hi) {
    return (uint_t)f2bf(lo) | ((uint_t)f2bf(hi) << 16);
}
__device__ __forceinline__ float bf_lo(uint_t u) { return __uint_as_float(u << 16); }
__device__ __forceinline__ float bf_hi(uint_t u) { return __uint_as_float(u & 0xFFFF0000u); }

__device__ __forceinline__ int wave_incl_scan(int v) {
    int lane = threadIdx.x & 63;
#pragma unroll
    for (int o = 1; o < 64; o <<= 1) {
        int t = __shfl_up(v, o);
        if (lane >= o) v += t;
    }
    return v;
}

// ---------------------------------------------------------------------------
// f32 -> bf16 conversion of the input features (8 elems/thread).
// ---------------------------------------------------------------------------
__global__ __launch_bounds__(256) void cvt_bf16(
    const float* __restrict__ in, uint_t* __restrict__ out, int n8)
{
    int i = blockIdx.x * 256 + threadIdx.x;
    if (i >= n8) return;
    const float4* p = reinterpret_cast<const float4*>(in) + 2 * i;
    float4 a = p[0], b = p[1];
    uint4 o;
    o.x = pack2bf(a.x, a.y); o.y = pack2bf(a.z, a.w);
    o.z = pack2bf(b.x, b.y); o.w = pack2bf(b.z, b.w);
    reinterpret_cast<uint4*>(out)[i] = o;
}

// ---------------------------------------------------------------------------
// Bucketed CSR build (measured-good, rounds 7-9). ebuf packed:
// (local_dst:10b << 17) | src:17b.
// ---------------------------------------------------------------------------
__global__ __launch_bounds__(256) void bucket_count(
    const int* __restrict__ dst, int* __restrict__ bcnt, int nE)
{
    __shared__ int cnt[NBUCK];
    int t = threadIdx.x;
    for (int i = t; i < NBUCK; i += 256) cnt[i] = 0;
    __syncthreads();
    int lo = blockIdx.x * CHUNK_A;
    int hi = lo + CHUNK_A;
    if (hi > nE) hi = nE;
    for (int e = lo + t; e < hi; e += 256)
        atomicAdd(&cnt[dst[e] >> BSHIFT], 1);
    __syncthreads();
    for (int i = t; i < NBUCK; i += 256)
        if (cnt[i]) atomicAdd(&bcnt[i], cnt[i]);
}

__global__ __launch_bounds__(128) void bucket_scan(
    const int* __restrict__ bcnt, int* __restrict__ bucket_base,
    int* __restrict__ cursor, int nE)
{
    int tid = threadIdx.x;  // NBUCK <= 128
    int v = tid < NBUCK ? bcnt[tid] : 0;
    int lane = tid & 63, w = tid >> 6;
    int incl = wave_incl_scan(v);
    __shared__ int ws[2];
    if (lane == 63) ws[w] = incl;
    __syncthreads();
    int off = (w == 1) ? ws[0] : 0;
    int excl = off + incl - v;
    if (tid < NBUCK) {
        bucket_base[tid] = excl;
        cursor[tid] = excl;
    }
    if (tid == 0) bucket_base[NBUCK] = nE;
}

__global__ __launch_bounds__(256) void bucket_pass(
    const int* __restrict__ src, const int* __restrict__ dst,
    int* __restrict__ cursor, int* __restrict__ ebuf, int nE)
{
    __shared__ int cnt[NBUCK];
    __shared__ int base[NBUCK];
    int t = threadIdx.x;
    for (int i = t; i < NBUCK; i += 256) cnt[i] = 0;
    __syncthreads();

    int lo = blockIdx.x * CHUNK_A;
    int hi = lo + CHUNK_A;
    if (hi > nE) hi = nE;

    for (int e = lo + t; e < hi; e += 256)
        atomicAdd(&cnt[dst[e] >> BSHIFT], 1);
    __syncthreads();

    for (int i = t; i < NBUCK; i += 256)
        base[i] = cnt[i] ? atomicAdd(&cursor[i], cnt[i]) : 0;
    __syncthreads();
    for (int i = t; i < NBUCK; i += 256) cnt[i] = 0;
    __syncthreads();

    for (int e = lo + t; e < hi; e += 256) {
        int d = dst[e];
        int b = d >> BSHIFT;
        int p = base[b] + atomicAdd(&cnt[b], 1);
        ebuf[p] = ((d & (BSIZE - 1)) << 17) | src[e];
    }
}

__global__ __launch_bounds__(256) void bucket_build(
    const int* __restrict__ bucket_base, const int* __restrict__ ebuf,
    int* __restrict__ row_start, int* __restrict__ ssrc)
{
    int b = blockIdx.x;
    int nlo = b << BSHIFT;
    int nhi = nlo + BSIZE;
    if (nhi > N_NODES_C) nhi = N_NODES_C;
    int nloc = nhi - nlo;

    __shared__ int degl[BSIZE];
    __shared__ int posl[BSIZE];
    __shared__ int ws[4];
    int t = threadIdx.x;

    for (int i = t; i < BSIZE; i += 256) degl[i] = 0;
    __syncthreads();

    int lo = bucket_base[b];
    int hi = bucket_base[b + 1];
    for (int e = lo + t; e < hi; e += 256)
        atomicAdd(&degl[ebuf[e] >> 17], 1);
    __syncthreads();

    int base4 = t * 4;
    int v0 = degl[base4 + 0], v1 = degl[base4 + 1];
    int v2 = degl[base4 + 2], v3 = degl[base4 + 3];
    int lsum = v0 + v1 + v2 + v3;
    int incl = wave_incl_scan(lsum);
    int lane = t & 63, w = t >> 6;
    if (lane == 63) ws[w] = incl;
    __syncthreads();
    int woff = 0;
    for (int i = 0; i < w; ++i) woff += ws[i];
    int pp = lo + woff + incl - lsum;
    if (base4 + 0 < nloc) { row_start[nlo + base4 + 0] = pp; posl[base4 + 0] = pp; } pp += v0;
    if (base4 + 1 < nloc) { row_start[nlo + base4 + 1] = pp; posl[base4 + 1] = pp; } pp += v1;
    if (base4 + 2 < nloc) { row_start[nlo + base4 + 2] = pp; posl[base4 + 2] = pp; } pp += v2;
    if (base4 + 3 < nloc) { row_start[nlo + base4 + 3] = pp; posl[base4 + 3] = pp; } pp += v3;
    if (t == 0 && nhi == N_NODES_C) row_start[N_NODES_C] = hi;
    __syncthreads();

    for (int e = lo + t; e < hi; e += 256) {
        int v = ebuf[e];
        int q = atomicAdd(&posl[v >> 17], 1);
        ssrc[q] = v & 0x1FFFF;
    }
}

// ---------------------------------------------------------------------------
// Gather-sum over bf16 rows, f32 accumulation, bf16 PACKED output (halves
// agg write traffic and downstream staging bytes).
// ---------------------------------------------------------------------------
template<int D>
__global__ __launch_bounds__(256) void gather_bf(
    const ushort_t* __restrict__ xb, const int* __restrict__ row_start,
    const int* __restrict__ ssrc, ushort_t* __restrict__ aggb, int nNodes)
{
    const int L = D / 8;        // lanes per node
    const int NPB = 256 / L;
    int local = threadIdx.x / L;
    int lane  = threadIdx.x % L;
    int n = blockIdx.x * NPB + local;
    if (n >= nNodes) return;
    int beg = row_start[n], end = row_start[n + 1];
    float4 accA = make_float4(0.f, 0.f, 0.f, 0.f);
    float4 accB = accA;
    int e = beg;
#pragma unroll 1
    for (; e + 1 < end; e += 2) {
        int s0 = ssrc[e], s1 = ssrc[e + 1];
        uint4 u0 = reinterpret_cast<const uint4*>(xb + (size_t)s0 * D)[lane];
        uint4 u1 = reinterpret_cast<const uint4*>(xb + (size_t)s1 * D)[lane];
        accA.x += bf_lo(u0.x) + bf_lo(u1.x);
        accA.y += bf_hi(u0.x) + bf_hi(u1.x);
        accA.z += bf_lo(u0.y) + bf_lo(u1.y);
        accA.w += bf_hi(u0.y) + bf_hi(u1.y);
        accB.x += bf_lo(u0.z) + bf_lo(u1.z);
        accB.y += bf_hi(u0.z) + bf_hi(u1.z);
        accB.z += bf_lo(u0.w) + bf_lo(u1.w);
        accB.w += bf_hi(u0.w) + bf_hi(u1.w);
    }
    if (e < end) {
        int s0 = ssrc[e];
        uint4 u0 = reinterpret_cast<const uint4*>(xb + (size_t)s0 * D)[lane];
        accA.x += bf_lo(u0.x); accA.y += bf_hi(u0.x);
        accA.z += bf_lo(u0.y); accA.w += bf_hi(u0.y);
        accB.x += bf_lo(u0.z); accB.y += bf_hi(u0.z);
        accB.z += bf_lo(u0.w); accB.w += bf_hi(u0.w);
    }
    uint4 o;
    o.x = pack2bf(accA.x, accA.y); o.y = pack2bf(accA.z, accA.w);
    o.z = pack2bf(accB.x, accB.y); o.w = pack2bf(accB.z, accB.w);
    reinterpret_cast<uint4*>(aggb + (size_t)n * D)[lane] = o;
}

// ---------------------------------------------------------------------------
// Node transform v5: BOTH staged inputs packed bf16 in LDS (halves stage
// footprint vs round 11 -> 3 blocks/CU for <64,64>), weights f32 in LDS.
// 2 nodes x 8 outputs per thread, k-loop rolled (#pragma unroll 2 over
// k-PAIRS). uint4 staging writes: <=2-way bank aliasing (free).
// ---------------------------------------------------------------------------
template<int DIN, int DOUT>
__global__ __launch_bounds__(256) void transform_bf2(
    const ushort_t* __restrict__ aggb, const ushort_t* __restrict__ xin,
    const float* __restrict__ w_rel, const float* __restrict__ bias,
    const float* __restrict__ w_root, ushort_t* __restrict__ out, int nNodes)
{
    constexpr int JB = 8;
    constexpr int TPN = DOUT / JB;      // threads per node
    constexpr int SLOTS = 256 / TPN;    // node slots
    constexpr int NT = 2;
    constexpr int NPB = SLOTS * NT;
    constexpr int PU = DIN / 2 + 4;     // uints per row; +4 keeps 16B align
                                        // and spreads banks (r*4+q mod 32)

    __shared__ float  wr[DIN * DOUT];
    __shared__ float  wt[DIN * DOUT];
    __shared__ uint_t au_s[NPB * PU];
    __shared__ uint_t xu_s[NPB * PU];

    {
        const float4* wr4 = reinterpret_cast<const float4*>(w_rel);
        const float4* wt4 = reinterpret_cast<const float4*>(w_root);
        float4* wrd = reinterpret_cast<float4*>(wr);
        float4* wtd = reinterpret_cast<float4*>(wt);
        for (int i = threadIdx.x; i < DIN * DOUT / 4; i += 256) {
            wrd[i] = wr4[i];
            wtd[i] = wt4[i];
        }
    }

    int n0 = blockIdx.x * NPB;
    constexpr int CH = DIN / 8;  // uint4 chunks per row
    for (int v = threadIdx.x; v < NPB * CH; v += 256) {
        int row = v / CH, c = v % CH;
        int n = n0 + row;
        uint4 a = make_uint4(0, 0, 0, 0);
        uint4 xx = a;
        if (n < nNodes) {
            a  = reinterpret_cast<const uint4*>(aggb + (size_t)n * DIN)[c];
            xx = reinterpret_cast<const uint4*>(xin  + (size_t)n * DIN)[c];
        }
        *reinterpret_cast<uint4*>(&au_s[row * PU + c * 4]) = a;
        *reinterpret_cast<uint4*>(&xu_s[row * PU + c * 4]) = xx;
    }
    __syncthreads();

    int slot = threadIdx.x / TPN;
    int j0 = (threadIdx.x % TPN) * JB;

    float4 biasLo = *reinterpret_cast<const float4*>(bias + j0);
    float4 biasHi = *reinterpret_cast<const float4*>(bias + j0 + 4);
    float4 accA0 = biasLo, accA1 = biasHi;
    float4 accB0 = biasLo, accB1 = biasHi;

    const uint_t* auA = &au_s[slot * PU];
    const uint_t* xuA = &xu_s[slot * PU];
    const uint_t* auB = auA + SLOTS * PU;
    const uint_t* xuB = xuA + SLOTS * PU;

    auto fma_step = [&](float aA, float xA, float aB, float xB,
                        const float* wk, const float* tk) {
        float4 w0 = *reinterpret_cast<const float4*>(wk);
        float4 w1 = *reinterpret_cast<const float4*>(wk + 4);
        float4 t0 = *reinterpret_cast<const float4*>(tk);
        float4 t1 = *reinterpret_cast<const float4*>(tk + 4);
        accA0.x += aA * w0.x + xA * t0.x;
        accA0.y += aA * w0.y + xA * t0.y;
        accA0.z += aA * w0.z + xA * t0.z;
        accA0.w += aA * w0.w + xA * t0.w;
        accA1.x += aA * w1.x + xA * t1.x;
        accA1.y += aA * w1.y + xA * t1.y;
        accA1.z += aA * w1.z + xA * t1.z;
        accA1.w += aA * w1.w + xA * t1.w;
        accB0.x += aB * w0.x + xB * t0.x;
        accB0.y += aB * w0.y + xB * t0.y;
        accB0.z += aB * w0.z + xB * t0.z;
        accB0.w += aB * w0.w + xB * t0.w;
        accB1.x += aB * w1.x + xB * t1.x;
        accB1.y += aB * w1.y + xB * t1.y;
        accB1.z += aB * w1.z + xB * t1.z;
        accB1.w += aB * w1.w + xB * t1.w;
    };

#pragma unroll 2
    for (int kk = 0; kk < DIN / 2; ++kk) {
        uint_t ua = auA[kk], ux = xuA[kk];
        uint_t ub = auB[kk], vx = xuB[kk];
        const float* wk = &wr[(2 * kk) * DOUT + j0];
        const float* tk = &wt[(2 * kk) * DOUT + j0];
        fma_step(bf_lo(ua), bf_lo(ux), bf_lo(ub), bf_lo(vx), wk, tk);
        fma_step(bf_hi(ua), bf_hi(ux), bf_hi(ub), bf_hi(vx), wk + DOUT, tk + DOUT);
    }

    int nA = n0 + slot;
    int nB = nA + SLOTS;
    if (nA < nNodes) {
        uint4 ob;
        ob.x = pack2bf(elu_f(accA0.x), elu_f(accA0.y));
        ob.y = pack2bf(elu_f(accA0.z), elu_f(accA0.w));
        ob.z = pack2bf(elu_f(accA1.x), elu_f(accA1.y));
        ob.w = pack2bf(elu_f(accA1.z), elu_f(accA1.w));
        *reinterpret_cast<uint4*>(out + (size_t)nA * DOUT + j0) = ob;
    }
    if (nB < nNodes) {
        uint4 ob;
        ob.x = pack2bf(elu_f(accB0.x), elu_f(accB0.y));
        ob.y = pack2bf(elu_f(accB0.z), elu_f(accB0.w));
        ob.z = pack2bf(elu_f(accB1.x), elu_f(accB1.y));
        ob.w = pack2bf(elu_f(accB1.z), elu_f(accB1.w));
        *reinterpret_cast<uint4*>(out + (size_t)nB * DOUT + j0) = ob;
    }
}

// ---------------------------------------------------------------------------
// Mean-pool over sorted batch, bf16 input, f32 sums.
// ---------------------------------------------------------------------------
#define POOL_CHUNK 256
__global__ __launch_bounds__(256) void pool_bf(
    const ushort_t* __restrict__ h, const int* __restrict__ batch,
    float* __restrict__ sums, float* __restrict__ cnts, int nNodes)
{
    int t = threadIdx.x;
    int j = t & 63;
    int sub = t >> 6;
    int start = blockIdx.x * POOL_CHUNK + sub;
    int end = blockIdx.x * POOL_CHUNK + POOL_CHUNK;
    if (end > nNodes) end = nNodes;
    if (start >= end) return;

    int g = batch[start];
    float acc = 0.f;
    float c = 0.f;
    for (int n = start; n < end; n += 4) {
        int gn = batch[n];
        if (gn != g) {
            unsafeAtomicAdd(&sums[(size_t)g * 64 + j], acc);
            if (j == 0) unsafeAtomicAdd(&cnts[g], c);
            acc = 0.f; c = 0.f; g = gn;
        }
        acc += __uint_as_float(((uint_t)h[(size_t)n * 64 + j]) << 16);
        c += 1.f;
    }
    unsafeAtomicAdd(&sums[(size_t)g * 64 + j], acc);
    if (j == 0) unsafeAtomicAdd(&cnts[g], c);
}

// ---------------------------------------------------------------------------
// MLP head + log_softmax: one 64-thread block per graph.
// ---------------------------------------------------------------------------
__global__ __launch_bounds__(64) void mlp_kernel(
    const float* __restrict__ sums, const float* __restrict__ cnts,
    const float* __restrict__ fw1, const float* __restrict__ fb1,
    const float* __restrict__ fw2, const float* __restrict__ fb2,
    const float* __restrict__ fw3, const float* __restrict__ fb3,
    float* __restrict__ out)
{
    int g = blockIdx.x;
    int j = threadIdx.x;
    __shared__ float p[64];
    __shared__ float z1[64];
    __shared__ float z2[32];
    __shared__ float z3[10];
    __shared__ float lse;

    float c = fmaxf(cnts[g], 1.f);
    p[j] = sums[(size_t)g * 64 + j] / c;
    __syncthreads();

    float a = fb1[j];
#pragma unroll
    for (int k = 0; k < 64; ++k) a += p[k] * fw1[k * 64 + j];
    z1[j] = elu_f(a);
    __syncthreads();

    if (j < 32) {
        float a2 = fb2[j];
#pragma unroll
        for (int k = 0; k < 64; ++k) a2 += z1[k] * fw2[k * 32 + j];
        z2[j] = elu_f(a2);
    }
    __syncthreads();

    if (j < 10) {
        float a3 = fb3[j];
#pragma unroll
        for (int k = 0; k < 32; ++k) a3 += z2[k] * fw3[k * 10 + j];
        z3[j] = a3;
    }
    __syncthreads();

    if (j == 0) {
        float m = -1e30f;
        for (int i = 0; i < 10; ++i) m = fmaxf(m, z3[i]);
        float s = 0.f;
        for (int i = 0; i < 10; ++i) s += expf(z3[i] - m);
        lse = logf(s) + m;
    }
    __syncthreads();

    if (j < 10) out[(size_t)g * 10 + j] = z3[j] - lse;
}

// ---------------------------------------------------------------------------
extern "C" void kernel_launch(void* const* d_in, const int* in_sizes, int n_in,
                              void* d_out, int out_size, void* d_ws, size_t ws_size,
                              hipStream_t stream)
{
    const float* x       = (const float*)d_in[0];
    const int*   ei      = (const int*)  d_in[1];
    const int*   batch   = (const int*)  d_in[2];
    const float* w1_rel  = (const float*)d_in[3];
    const float* b1      = (const float*)d_in[4];
    const float* w1_root = (const float*)d_in[5];
    const float* w2_rel  = (const float*)d_in[6];
    const float* b2      = (const float*)d_in[7];
    const float* w2_root = (const float*)d_in[8];
    const float* w3_rel  = (const float*)d_in[9];
    const float* b3      = (const float*)d_in[10];
    const float* w3_root = (const float*)d_in[11];
    const float* fw1     = (const float*)d_in[12];
    const float* fb1     = (const float*)d_in[13];
    const float* fw2     = (const float*)d_in[14];
    const float* fb2     = (const float*)d_in[15];
    const float* fw3     = (const float*)d_in[16];
    const float* fb3     = (const float*)d_in[17];
    float* out = (float*)d_out;

    const int* src = ei;
    const int* dst = ei + N_EDGES_C;

    // workspace layout (bf16 feature buffers)
    ushort_t* aggb = (ushort_t*)d_ws;                        // N*64 bf16 (12.8MB)
    ushort_t* xb  = aggb + (size_t)N_NODES_C * 64;           // N*32 bf16
    ushort_t* h1  = xb + (size_t)N_NODES_C * 32;             // N*32 bf16
    ushort_t* h2  = h1 + (size_t)N_NODES_C * 32;             // N*64 bf16
    ushort_t* h3  = h2 + (size_t)N_NODES_C * 64;             // N*64 bf16
    float* sums = (float*)(h3 + (size_t)N_NODES_C * 64);     // 512*64 f
    float* cnts = sums + (size_t)N_GRAPHS_C * 64;            // 512 f
    int*   row_start = (int*)(cnts + N_GRAPHS_C);            // N+1 int
    int*   bcnt = row_start + N_NODES_C + 1;                 // NBUCK
    int*   bucket_base = bcnt + NBUCK;                       // NBUCK+1
    int*   cursor = bucket_base + NBUCK + 1;                 // NBUCK
    int*   ssrc = cursor + NBUCK;                            // nE int
    int*   ebuf = (int*)aggb;  // aliased (12.8MB >= 6.4MB); CSR build done
                               // before layer-1 gather writes aggb

    // ---- input f32 -> bf16 ----
    cvt_bf16<<<(N_NODES_C * 32 / 8 + 255) / 256, 256, 0, stream>>>(
        x, (uint_t*)xb, N_NODES_C * 32 / 8);

    // ---- bucketed CSR build ----
    hipMemsetAsync(bcnt, 0, NBUCK * sizeof(int), stream);
    bucket_count<<<(N_EDGES_C + CHUNK_A - 1) / CHUNK_A, 256, 0, stream>>>(
        dst, bcnt, N_EDGES_C);
    bucket_scan<<<1, 128, 0, stream>>>(bcnt, bucket_base, cursor, N_EDGES_C);
    bucket_pass<<<(N_EDGES_C + CHUNK_A - 1) / CHUNK_A, 256, 0, stream>>>(
        src, dst, cursor, ebuf, N_EDGES_C);
    bucket_build<<<NBUCK, 256, 0, stream>>>(bucket_base, ebuf, row_start, ssrc);

    // ---- layer 1: 32 -> 32, xb -> h1 ----
    gather_bf<32><<<(N_NODES_C + 63) / 64, 256, 0, stream>>>(
        xb, row_start, ssrc, aggb, N_NODES_C);
    transform_bf2<32, 32><<<(N_NODES_C + 127) / 128, 256, 0, stream>>>(
        aggb, xb, w1_rel, b1, w1_root, h1, N_NODES_C);

    // ---- layer 2: 32 -> 64, h1 -> h2 ----
    gather_bf<32><<<(N_NODES_C + 63) / 64, 256, 0, stream>>>(
        h1, row_start, ssrc, aggb, N_NODES_C);
    transform_bf2<32, 64><<<(N_NODES_C + 63) / 64, 256, 0, stream>>>(
        aggb, h1, w2_rel, b2, w2_root, h2, N_NODES_C);

    // ---- layer 3: 64 -> 64, h2 -> h3 ----
    gather_bf<64><<<(N_NODES_C + 31) / 32, 256, 0, stream>>>(
        h2, row_start, ssrc, aggb, N_NODES_C);
    transform_bf2<64, 64><<<(N_NODES_C + 63) / 64, 256, 0, stream>>>(
        aggb, h2, w3_rel, b3, w3_root, h3, N_NODES_C);

    // ---- mean pool ----
    hipMemsetAsync(sums, 0, ((size_t)N_GRAPHS_C * 64 + N_GRAPHS_C) * sizeof(float), stream);
    pool_bf<<<(N_NODES_C + POOL_CHUNK - 1) / POOL_CHUNK, 256, 0, stream>>>(
        h3, batch, sums, cnts, N_NODES_C);

    // ---- MLP head + log_softmax ----
    mlp_kernel<<<N_GRAPHS_C, 64, 0, stream>>>(
        sums, cnts, fw1, fb1, fw2, fb2, fw3, fb3, out);
}

// Round 13
// 277.670 us; speedup vs baseline: 1.0804x; 1.0804x over previous
//
#include <hip/hip_runtime.h>
#include <hip/hip_bf16.h>
#include <math.h>

#define N_NODES_C 100000
#define N_EDGES_C 1600000
#define N_GRAPHS_C 512
#define BSHIFT 10
#define BSIZE (1 << BSHIFT)
#define NBUCK ((N_NODES_C + BSIZE - 1) >> BSHIFT)   // 98
#define CHUNK_A 8192

typedef unsigned int  uint_t;
typedef unsigned short ushort_t;
typedef __attribute__((ext_vector_type(8))) short bf16x8;
typedef __attribute__((ext_vector_type(4))) float f32x4;

__device__ __forceinline__ float elu_f(float x) { return x > 0.f ? x : expm1f(x); }

// bf16 helpers (RNE pack, shift unpack). Finite values only.
__device__ __forceinline__ ushort_t f2bf(float f) {
    uint_t u = __float_as_uint(f);
    u += 0x7FFFu + ((u >> 16) & 1u);
    return (ushort_t)(u >> 16);
}
__device__ __forceinline__ uint_t pack2bf(float lo, float hi) {
    return (uint_t)f2bf(lo) | ((uint_t)f2bf(hi) << 16);
}
__device__ __forceinline__ float bf_lo(uint_t u) { return __uint_as_float(u << 16); }
__device__ __forceinline__ float bf_hi(uint_t u) { return __uint_as_float(u & 0xFFFF0000u); }

__device__ __forceinline__ int wave_incl_scan(int v) {
    int lane = threadIdx.x & 63;
#pragma unroll
    for (int o = 1; o < 64; o <<= 1) {
        int t = __shfl_up(v, o);
        if (lane >= o) v += t;
    }
    return v;
}

// ---------------------------------------------------------------------------
// f32 -> bf16 conversion of the input features (8 elems/thread).
// ---------------------------------------------------------------------------
__global__ __launch_bounds__(256) void cvt_bf16(
    const float* __restrict__ in, uint_t* __restrict__ out, int n8)
{
    int i = blockIdx.x * 256 + threadIdx.x;
    if (i >= n8) return;
    const float4* p = reinterpret_cast<const float4*>(in) + 2 * i;
    float4 a = p[0], b = p[1];
    uint4 o;
    o.x = pack2bf(a.x, a.y); o.y = pack2bf(a.z, a.w);
    o.z = pack2bf(b.x, b.y); o.w = pack2bf(b.z, b.w);
    reinterpret_cast<uint4*>(out)[i] = o;
}

// ---------------------------------------------------------------------------
// Build transposed+concatenated bf16 weights for the MFMA transform:
//   wcatT[n][k] = (k < DIN ? w_rel[k][n] : w_root[k-DIN][n]),  [DOUT][2*DIN]
// ---------------------------------------------------------------------------
__global__ __launch_bounds__(256) void build_wcatT(
    const float* __restrict__ wr, const float* __restrict__ wt,
    ushort_t* __restrict__ o, int DIN, int DOUT)
{
    int idx = blockIdx.x * 256 + threadIdx.x;
    int KT = 2 * DIN;
    if (idx >= DOUT * KT) return;
    int n = idx / KT, k = idx % KT;
    float v = (k < DIN) ? wr[k * DOUT + n] : wt[(k - DIN) * DOUT + n];
    o[idx] = f2bf(v);
}

// ---------------------------------------------------------------------------
// Bucketed CSR build (measured-good, rounds 7-9). ebuf packed:
// (local_dst:10b << 17) | src:17b.
// ---------------------------------------------------------------------------
__global__ __launch_bounds__(256) void bucket_count(
    const int* __restrict__ dst, int* __restrict__ bcnt, int nE)
{
    __shared__ int cnt[NBUCK];
    int t = threadIdx.x;
    for (int i = t; i < NBUCK; i += 256) cnt[i] = 0;
    __syncthreads();
    int lo = blockIdx.x * CHUNK_A;
    int hi = lo + CHUNK_A;
    if (hi > nE) hi = nE;
    for (int e = lo + t; e < hi; e += 256)
        atomicAdd(&cnt[dst[e] >> BSHIFT], 1);
    __syncthreads();
    for (int i = t; i < NBUCK; i += 256)
        if (cnt[i]) atomicAdd(&bcnt[i], cnt[i]);
}

__global__ __launch_bounds__(128) void bucket_scan(
    const int* __restrict__ bcnt, int* __restrict__ bucket_base,
    int* __restrict__ cursor, int nE)
{
    int tid = threadIdx.x;  // NBUCK <= 128
    int v = tid < NBUCK ? bcnt[tid] : 0;
    int lane = tid & 63, w = tid >> 6;
    int incl = wave_incl_scan(v);
    __shared__ int ws[2];
    if (lane == 63) ws[w] = incl;
    __syncthreads();
    int off = (w == 1) ? ws[0] : 0;
    int excl = off + incl - v;
    if (tid < NBUCK) {
        bucket_base[tid] = excl;
        cursor[tid] = excl;
    }
    if (tid == 0) bucket_base[NBUCK] = nE;
}

__global__ __launch_bounds__(256) void bucket_pass(
    const int* __restrict__ src, const int* __restrict__ dst,
    int* __restrict__ cursor, int* __restrict__ ebuf, int nE)
{
    __shared__ int cnt[NBUCK];
    __shared__ int base[NBUCK];
    int t = threadIdx.x;
    for (int i = t; i < NBUCK; i += 256) cnt[i] = 0;
    __syncthreads();

    int lo = blockIdx.x * CHUNK_A;
    int hi = lo + CHUNK_A;
    if (hi > nE) hi = nE;

    for (int e = lo + t; e < hi; e += 256)
        atomicAdd(&cnt[dst[e] >> BSHIFT], 1);
    __syncthreads();

    for (int i = t; i < NBUCK; i += 256)
        base[i] = cnt[i] ? atomicAdd(&cursor[i], cnt[i]) : 0;
    __syncthreads();
    for (int i = t; i < NBUCK; i += 256) cnt[i] = 0;
    __syncthreads();

    for (int e = lo + t; e < hi; e += 256) {
        int d = dst[e];
        int b = d >> BSHIFT;
        int p = base[b] + atomicAdd(&cnt[b], 1);
        ebuf[p] = ((d & (BSIZE - 1)) << 17) | src[e];
    }
}

__global__ __launch_bounds__(256) void bucket_build(
    const int* __restrict__ bucket_base, const int* __restrict__ ebuf,
    int* __restrict__ row_start, int* __restrict__ ssrc)
{
    int b = blockIdx.x;
    int nlo = b << BSHIFT;
    int nhi = nlo + BSIZE;
    if (nhi > N_NODES_C) nhi = N_NODES_C;
    int nloc = nhi - nlo;

    __shared__ int degl[BSIZE];
    __shared__ int posl[BSIZE];
    __shared__ int ws[4];
    int t = threadIdx.x;

    for (int i = t; i < BSIZE; i += 256) degl[i] = 0;
    __syncthreads();

    int lo = bucket_base[b];
    int hi = bucket_base[b + 1];
    for (int e = lo + t; e < hi; e += 256)
        atomicAdd(&degl[ebuf[e] >> 17], 1);
    __syncthreads();

    int base4 = t * 4;
    int v0 = degl[base4 + 0], v1 = degl[base4 + 1];
    int v2 = degl[base4 + 2], v3 = degl[base4 + 3];
    int lsum = v0 + v1 + v2 + v3;
    int incl = wave_incl_scan(lsum);
    int lane = t & 63, w = t >> 6;
    if (lane == 63) ws[w] = incl;
    __syncthreads();
    int woff = 0;
    for (int i = 0; i < w; ++i) woff += ws[i];
    int pp = lo + woff + incl - lsum;
    if (base4 + 0 < nloc) { row_start[nlo + base4 + 0] = pp; posl[base4 + 0] = pp; } pp += v0;
    if (base4 + 1 < nloc) { row_start[nlo + base4 + 1] = pp; posl[base4 + 1] = pp; } pp += v1;
    if (base4 + 2 < nloc) { row_start[nlo + base4 + 2] = pp; posl[base4 + 2] = pp; } pp += v2;
    if (base4 + 3 < nloc) { row_start[nlo + base4 + 3] = pp; posl[base4 + 3] = pp; } pp += v3;
    if (t == 0 && nhi == N_NODES_C) row_start[N_NODES_C] = hi;
    __syncthreads();

    for (int e = lo + t; e < hi; e += 256) {
        int v = ebuf[e];
        int q = atomicAdd(&posl[v >> 17], 1);
        ssrc[q] = v & 0x1FFFF;
    }
}

// ---------------------------------------------------------------------------
// Gather-sum over bf16 rows, f32 accumulation, bf16 packed output.
// ---------------------------------------------------------------------------
template<int D>
__global__ __launch_bounds__(256) void gather_bf(
    const ushort_t* __restrict__ xb, const int* __restrict__ row_start,
    const int* __restrict__ ssrc, ushort_t* __restrict__ aggb, int nNodes)
{
    const int L = D / 8;        // lanes per node
    const int NPB = 256 / L;
    int local = threadIdx.x / L;
    int lane  = threadIdx.x % L;
    int n = blockIdx.x * NPB + local;
    if (n >= nNodes) return;
    int beg = row_start[n], end = row_start[n + 1];
    float4 accA = make_float4(0.f, 0.f, 0.f, 0.f);
    float4 accB = accA;
    int e = beg;
#pragma unroll 1
    for (; e + 1 < end; e += 2) {
        int s0 = ssrc[e], s1 = ssrc[e + 1];
        uint4 u0 = reinterpret_cast<const uint4*>(xb + (size_t)s0 * D)[lane];
        uint4 u1 = reinterpret_cast<const uint4*>(xb + (size_t)s1 * D)[lane];
        accA.x += bf_lo(u0.x) + bf_lo(u1.x);
        accA.y += bf_hi(u0.x) + bf_hi(u1.x);
        accA.z += bf_lo(u0.y) + bf_lo(u1.y);
        accA.w += bf_hi(u0.y) + bf_hi(u1.y);
        accB.x += bf_lo(u0.z) + bf_lo(u1.z);
        accB.y += bf_hi(u0.z) + bf_hi(u1.z);
        accB.z += bf_lo(u0.w) + bf_lo(u1.w);
        accB.w += bf_hi(u0.w) + bf_hi(u1.w);
    }
    if (e < end) {
        int s0 = ssrc[e];
        uint4 u0 = reinterpret_cast<const uint4*>(xb + (size_t)s0 * D)[lane];
        accA.x += bf_lo(u0.x); accA.y += bf_hi(u0.x);
        accA.z += bf_lo(u0.y); accA.w += bf_hi(u0.y);
        accB.x += bf_lo(u0.z); accB.y += bf_hi(u0.z);
        accB.z += bf_lo(u0.w); accB.w += bf_hi(u0.w);
    }
    uint4 o;
    o.x = pack2bf(accA.x, accA.y); o.y = pack2bf(accA.z, accA.w);
    o.z = pack2bf(accB.x, accB.y); o.w = pack2bf(accB.z, accB.w);
    reinterpret_cast<uint4*>(aggb + (size_t)n * D)[lane] = o;
}

// ---------------------------------------------------------------------------
// MFMA node transform: out = ELU( [agg | x] @ wcatT^T + bias ), bf16 in/out.
// v_mfma_f32_16x16x32_bf16 per wave: 16 nodes x 16 cols, K chained.
// Fragment layouts (guide §3, m89/m91/m162-verified):
//   A: lane l holds A[l&15][ kb*32 + (l>>4)*4 + (j&3) + 16*(j>>2) ]
//   B: lane l holds B[ same k pattern ][l&15]   (B[k][n] = wcatT[n][k])
//   D: lane l reg r -> row (l>>4)*4 + r, col l&15
// ---------------------------------------------------------------------------
template<int DIN, int DOUT>
__global__ __launch_bounds__(256) void transform_mfma(
    const ushort_t* __restrict__ aggb, const ushort_t* __restrict__ xb,
    const ushort_t* __restrict__ wcatT, const float* __restrict__ bias,
    ushort_t* __restrict__ out, int nNodes)
{
    constexpr int KT = 2 * DIN;        // total K
    constexpr int NKB = KT / 32;       // K-blocks per chain (2 or 4)
    constexpr int NTILES = DOUT / 16;  // column tiles (2 or 4)
    constexpr int MPB = 256;           // nodes per block

    int wid  = threadIdx.x >> 6;
    int lane = threadIdx.x & 63;
    int l15  = lane & 15;
    int lg   = lane >> 4;

    int ntile, mstep, mofs;
    if (NTILES == 4) { ntile = wid;     mstep = 16; mofs = 0; }
    else             { ntile = wid & 1; mstep = 32; mofs = (wid >> 1) * 16; }
    int n0 = ntile * 16;

    // B fragments (loaded once, reused for all m-tiles)
    bf16x8 bfrag[NKB];
    {
        const ushort_t* wrow = wcatT + (size_t)(n0 + l15) * KT;
#pragma unroll
        for (int kb = 0; kb < NKB; ++kb) {
            int kbase = kb * 32 + lg * 4;
            union { uint2 u[2]; bf16x8 v; } cvt;
            cvt.u[0] = *reinterpret_cast<const uint2*>(wrow + kbase);
            cvt.u[1] = *reinterpret_cast<const uint2*>(wrow + kbase + 16);
            bfrag[kb] = cvt.v;
        }
    }

    float bj = bias[n0 + l15];

    int base = blockIdx.x * MPB;
    for (int m0 = base + mofs; m0 < base + MPB; m0 += mstep) {
        int row = m0 + l15;
        bool valid_r = row < nNodes;
        f32x4 acc = {0.f, 0.f, 0.f, 0.f};
#pragma unroll
        for (int kb = 0; kb < NKB; ++kb) {
            const ushort_t* srcp = (kb < NKB / 2) ? aggb : xb;
            int kloc = (kb < NKB / 2) ? kb * 32 : kb * 32 - DIN;
            union { uint2 u[2]; bf16x8 v; } cvt;
            if (valid_r) {
                const ushort_t* arow = srcp + (size_t)row * DIN + kloc + lg * 4;
                cvt.u[0] = *reinterpret_cast<const uint2*>(arow);
                cvt.u[1] = *reinterpret_cast<const uint2*>(arow + 16);
            } else {
                cvt.u[0] = make_uint2(0, 0);
                cvt.u[1] = make_uint2(0, 0);
            }
            acc = __builtin_amdgcn_mfma_f32_16x16x32_bf16(cvt.v, bfrag[kb], acc, 0, 0, 0);
        }
#pragma unroll
        for (int r = 0; r < 4; ++r) {
            int orow = m0 + lg * 4 + r;
            if (orow < nNodes)
                out[(size_t)orow * DOUT + n0 + l15] = f2bf(elu_f(acc[r] + bj));
        }
    }
}

// ---------------------------------------------------------------------------
// Mean-pool over sorted batch, bf16 input, f32 sums.
// ---------------------------------------------------------------------------
#define POOL_CHUNK 256
__global__ __launch_bounds__(256) void pool_bf(
    const ushort_t* __restrict__ h, const int* __restrict__ batch,
    float* __restrict__ sums, float* __restrict__ cnts, int nNodes)
{
    int t = threadIdx.x;
    int j = t & 63;
    int sub = t >> 6;
    int start = blockIdx.x * POOL_CHUNK + sub;
    int end = blockIdx.x * POOL_CHUNK + POOL_CHUNK;
    if (end > nNodes) end = nNodes;
    if (start >= end) return;

    int g = batch[start];
    float acc = 0.f;
    float c = 0.f;
    for (int n = start; n < end; n += 4) {
        int gn = batch[n];
        if (gn != g) {
            unsafeAtomicAdd(&sums[(size_t)g * 64 + j], acc);
            if (j == 0) unsafeAtomicAdd(&cnts[g], c);
            acc = 0.f; c = 0.f; g = gn;
        }
        acc += __uint_as_float(((uint_t)h[(size_t)n * 64 + j]) << 16);
        c += 1.f;
    }
    unsafeAtomicAdd(&sums[(size_t)g * 64 + j], acc);
    if (j == 0) unsafeAtomicAdd(&cnts[g], c);
}

// ---------------------------------------------------------------------------
// MLP head + log_softmax: one 64-thread block per graph.
// ---------------------------------------------------------------------------
__global__ __launch_bounds__(64) void mlp_kernel(
    const float* __restrict__ sums, const float* __restrict__ cnts,
    const float* __restrict__ fw1, const float* __restrict__ fb1,
    const float* __restrict__ fw2, const float* __restrict__ fb2,
    const float* __restrict__ fw3, const float* __restrict__ fb3,
    float* __restrict__ out)
{
    int g = blockIdx.x;
    int j = threadIdx.x;
    __shared__ float p[64];
    __shared__ float z1[64];
    __shared__ float z2[32];
    __shared__ float z3[10];
    __shared__ float lse;

    float c = fmaxf(cnts[g], 1.f);
    p[j] = sums[(size_t)g * 64 + j] / c;
    __syncthreads();

    float a = fb1[j];
#pragma unroll
    for (int k = 0; k < 64; ++k) a += p[k] * fw1[k * 64 + j];
    z1[j] = elu_f(a);
    __syncthreads();

    if (j < 32) {
        float a2 = fb2[j];
#pragma unroll
        for (int k = 0; k < 64; ++k) a2 += z1[k] * fw2[k * 32 + j];
        z2[j] = elu_f(a2);
    }
    __syncthreads();

    if (j < 10) {
        float a3 = fb3[j];
#pragma unroll
        for (int k = 0; k < 32; ++k) a3 += z2[k] * fw3[k * 10 + j];
        z3[j] = a3;
    }
    __syncthreads();

    if (j == 0) {
        float m = -1e30f;
        for (int i = 0; i < 10; ++i) m = fmaxf(m, z3[i]);
        float s = 0.f;
        for (int i = 0; i < 10; ++i) s += expf(z3[i] - m);
        lse = logf(s) + m;
    }
    __syncthreads();

    if (j < 10) out[(size_t)g * 10 + j] = z3[j] - lse;
}

// ---------------------------------------------------------------------------
extern "C" void kernel_launch(void* const* d_in, const int* in_sizes, int n_in,
                              void* d_out, int out_size, void* d_ws, size_t ws_size,
                              hipStream_t stream)
{
    const float* x       = (const float*)d_in[0];
    const int*   ei      = (const int*)  d_in[1];
    const int*   batch   = (const int*)  d_in[2];
    const float* w1_rel  = (const float*)d_in[3];
    const float* b1      = (const float*)d_in[4];
    const float* w1_root = (const float*)d_in[5];
    const float* w2_rel  = (const float*)d_in[6];
    const float* b2      = (const float*)d_in[7];
    const float* w2_root = (const float*)d_in[8];
    const float* w3_rel  = (const float*)d_in[9];
    const float* b3      = (const float*)d_in[10];
    const float* w3_root = (const float*)d_in[11];
    const float* fw1     = (const float*)d_in[12];
    const float* fb1     = (const float*)d_in[13];
    const float* fw2     = (const float*)d_in[14];
    const float* fb2     = (const float*)d_in[15];
    const float* fw3     = (const float*)d_in[16];
    const float* fb3     = (const float*)d_in[17];
    float* out = (float*)d_out;

    const int* src = ei;
    const int* dst = ei + N_EDGES_C;

    // workspace layout (bf16 feature buffers)
    ushort_t* aggb = (ushort_t*)d_ws;                        // N*64 bf16 (12.8MB)
    ushort_t* xb  = aggb + (size_t)N_NODES_C * 64;           // N*32 bf16
    ushort_t* h1  = xb + (size_t)N_NODES_C * 32;             // N*32 bf16
    ushort_t* h2  = h1 + (size_t)N_NODES_C * 32;             // N*64 bf16
    ushort_t* h3  = h2 + (size_t)N_NODES_C * 64;             // N*64 bf16
    float* sums = (float*)(h3 + (size_t)N_NODES_C * 64);     // 512*64 f
    float* cnts = sums + (size_t)N_GRAPHS_C * 64;            // 512 f
    int*   row_start = (int*)(cnts + N_GRAPHS_C);            // N+1 int
    int*   bcnt = row_start + N_NODES_C + 1;                 // NBUCK
    int*   bucket_base = bcnt + NBUCK;                       // NBUCK+1
    int*   cursor = bucket_base + NBUCK + 1;                 // NBUCK
    int*   ssrc = cursor + NBUCK;                            // nE int
    ushort_t* wc1 = (ushort_t*)((((size_t)(ssrc + N_EDGES_C)) + 15) & ~(size_t)15);
    ushort_t* wc2 = wc1 + 2048;                              // [32][64]
    ushort_t* wc3 = wc2 + 4096;                              // [64][128] (after [64][64])
    int*   ebuf = (int*)aggb;  // aliased (12.8MB >= 6.4MB); CSR build done
                               // before layer-1 gather writes aggb

    // ---- input f32 -> bf16; weight prep ----
    cvt_bf16<<<(N_NODES_C * 32 / 8 + 255) / 256, 256, 0, stream>>>(
        x, (uint_t*)xb, N_NODES_C * 32 / 8);
    build_wcatT<<<8, 256, 0, stream>>>(w1_rel, w1_root, wc1, 32, 32);
    build_wcatT<<<16, 256, 0, stream>>>(w2_rel, w2_root, wc2, 32, 64);
    build_wcatT<<<32, 256, 0, stream>>>(w3_rel, w3_root, wc3, 64, 64);

    // ---- bucketed CSR build ----
    hipMemsetAsync(bcnt, 0, NBUCK * sizeof(int), stream);
    bucket_count<<<(N_EDGES_C + CHUNK_A - 1) / CHUNK_A, 256, 0, stream>>>(
        dst, bcnt, N_EDGES_C);
    bucket_scan<<<1, 128, 0, stream>>>(bcnt, bucket_base, cursor, N_EDGES_C);
    bucket_pass<<<(N_EDGES_C + CHUNK_A - 1) / CHUNK_A, 256, 0, stream>>>(
        src, dst, cursor, ebuf, N_EDGES_C);
    bucket_build<<<NBUCK, 256, 0, stream>>>(bucket_base, ebuf, row_start, ssrc);

    const int TB = (N_NODES_C + 255) / 256;  // transform blocks (256 nodes each)

    // ---- layer 1: 32 -> 32, xb -> h1 ----
    gather_bf<32><<<(N_NODES_C + 63) / 64, 256, 0, stream>>>(
        xb, row_start, ssrc, aggb, N_NODES_C);
    transform_mfma<32, 32><<<TB, 256, 0, stream>>>(
        aggb, xb, wc1, b1, h1, N_NODES_C);

    // ---- layer 2: 32 -> 64, h1 -> h2 ----
    gather_bf<32><<<(N_NODES_C + 63) / 64, 256, 0, stream>>>(
        h1, row_start, ssrc, aggb, N_NODES_C);
    transform_mfma<32, 64><<<TB, 256, 0, stream>>>(
        aggb, h1, wc2, b2, h2, N_NODES_C);

    // ---- layer 3: 64 -> 64, h2 -> h3 ----
    gather_bf<64><<<(N_NODES_C + 31) / 32, 256, 0, stream>>>(
        h2, row_start, ssrc, aggb, N_NODES_C);
    transform_mfma<64, 64><<<TB, 256, 0, stream>>>(
        aggb, h2, wc3, b3, h3, N_NODES_C);

    // ---- mean pool ----
    hipMemsetAsync(sums, 0, ((size_t)N_GRAPHS_C * 64 + N_GRAPHS_C) * sizeof(float), stream);
    pool_bf<<<(N_NODES_C + POOL_CHUNK - 1) / POOL_CHUNK, 256, 0, stream>>>(
        h3, batch, sums, cnts, N_NODES_C);

    // ---- MLP head + log_softmax ----
    mlp_kernel<<<N_GRAPHS_C, 64, 0, stream>>>(
        sums, cnts, fw1, fb1, fw2, fb2, fw3, fb3, out);
}

// Round 14
// 250.720 us; speedup vs baseline: 1.1966x; 1.1075x over previous
//
#include <hip/hip_runtime.h>
#include <hip/hip_bf16.h>
#include <math.h>

#define N_NODES_C 100000
#define N_EDGES_C 1600000
#define N_GRAPHS_C 512
#define BSHIFT 10
#define BSIZE (1 << BSHIFT)
#define NBUCK ((N_NODES_C + BSIZE - 1) >> BSHIFT)   // 98
#define CHUNK_A 2048
#define NCH ((N_EDGES_C + CHUNK_A - 1) / CHUNK_A)   // 782

typedef unsigned int  uint_t;
typedef unsigned short ushort_t;
typedef __attribute__((ext_vector_type(8))) short bf16x8;
typedef __attribute__((ext_vector_type(4))) float f32x4;

__device__ __forceinline__ float elu_f(float x) { return x > 0.f ? x : expm1f(x); }

// bf16 helpers (RNE pack, shift unpack). Finite values only.
__device__ __forceinline__ ushort_t f2bf(float f) {
    uint_t u = __float_as_uint(f);
    u += 0x7FFFu + ((u >> 16) & 1u);
    return (ushort_t)(u >> 16);
}
__device__ __forceinline__ uint_t pack2bf(float lo, float hi) {
    return (uint_t)f2bf(lo) | ((uint_t)f2bf(hi) << 16);
}
__device__ __forceinline__ float bf_lo(uint_t u) { return __uint_as_float(u << 16); }
__device__ __forceinline__ float bf_hi(uint_t u) { return __uint_as_float(u & 0xFFFF0000u); }

__device__ __forceinline__ int wave_incl_scan(int v) {
    int lane = threadIdx.x & 63;
#pragma unroll
    for (int o = 1; o < 64; o <<= 1) {
        int t = __shfl_up(v, o);
        if (lane >= o) v += t;
    }
    return v;
}

// ---------------------------------------------------------------------------
// f32 -> bf16 conversion of the input features (8 elems/thread).
// ---------------------------------------------------------------------------
__global__ __launch_bounds__(256) void cvt_bf16(
    const float* __restrict__ in, uint_t* __restrict__ out, int n8)
{
    int i = blockIdx.x * 256 + threadIdx.x;
    if (i >= n8) return;
    const float4* p = reinterpret_cast<const float4*>(in) + 2 * i;
    float4 a = p[0], b = p[1];
    uint4 o;
    o.x = pack2bf(a.x, a.y); o.y = pack2bf(a.z, a.w);
    o.z = pack2bf(b.x, b.y); o.w = pack2bf(b.z, b.w);
    reinterpret_cast<uint4*>(out)[i] = o;
}

// ---------------------------------------------------------------------------
// Build transposed+concatenated bf16 weights for the MFMA transform.
// ---------------------------------------------------------------------------
__global__ __launch_bounds__(256) void build_wcatT(
    const float* __restrict__ wr, const float* __restrict__ wt,
    ushort_t* __restrict__ o, int DIN, int DOUT)
{
    int idx = blockIdx.x * 256 + threadIdx.x;
    int KT = 2 * DIN;
    if (idx >= DOUT * KT) return;
    int n = idx / KT, k = idx % KT;
    float v = (k < DIN) ? wr[k * DOUT + n] : wt[(k - DIN) * DOUT + n];
    o[idx] = f2bf(v);
}

// ---------------------------------------------------------------------------
// Bucketed CSR build v2: deterministic per-chunk bases, single atomic pass.
//  1) bucket_count: per-chunk LDS histogram -> ccnt[b][c]
//  2) scan_chunks: wave per bucket, exclusive scan over chunks -> cbase, btot
//  3) bucket_scan: 1-block exclusive scan of btot -> bucket_base
//  4) bucket_pass: ONE LDS-atomic pass; p = bucket_base+cbase+cnt[b]++
//  5) bucket_build: per bucket deg-histogram + scan -> row_start, ssrc fill
// ---------------------------------------------------------------------------
__global__ __launch_bounds__(256) void bucket_count(
    const int* __restrict__ dst, int* __restrict__ ccnt, int nE)
{
    __shared__ int cnt[NBUCK];
    int t = threadIdx.x;
    for (int i = t; i < NBUCK; i += 256) cnt[i] = 0;
    __syncthreads();
    int lo = blockIdx.x * CHUNK_A;
    int hi = lo + CHUNK_A;
    if (hi > nE) hi = nE;
    for (int e = lo + t; e < hi; e += 256)
        atomicAdd(&cnt[dst[e] >> BSHIFT], 1);
    __syncthreads();
    for (int i = t; i < NBUCK; i += 256)
        ccnt[(size_t)i * NCH + blockIdx.x] = cnt[i];
}

__global__ __launch_bounds__(256) void scan_chunks(
    const int* __restrict__ ccnt, int* __restrict__ cbase, int* __restrict__ btot)
{
    int wid = blockIdx.x * 4 + (threadIdx.x >> 6);  // bucket
    int lane = threadIdx.x & 63;
    if (wid >= NBUCK) return;
    const int* row = ccnt + (size_t)wid * NCH;
    int* orow = cbase + (size_t)wid * NCH;
    int running = 0;
    for (int c0 = 0; c0 < NCH; c0 += 64) {
        int c = c0 + lane;
        int v = (c < NCH) ? row[c] : 0;
        int incl = wave_incl_scan(v);
        if (c < NCH) orow[c] = running + incl - v;
        running += __shfl(incl, 63);
    }
    if (lane == 0) btot[wid] = running;
}

__global__ __launch_bounds__(128) void bucket_scan(
    const int* __restrict__ btot, int* __restrict__ bucket_base, int nE)
{
    int tid = threadIdx.x;  // NBUCK <= 128
    int v = tid < NBUCK ? btot[tid] : 0;
    int lane = tid & 63, w = tid >> 6;
    int incl = wave_incl_scan(v);
    __shared__ int ws[2];
    if (lane == 63) ws[w] = incl;
    __syncthreads();
    int off = (w == 1) ? ws[0] : 0;
    if (tid < NBUCK) bucket_base[tid] = off + incl - v;
    if (tid == 0) bucket_base[NBUCK] = nE;
}

__global__ __launch_bounds__(256) void bucket_pass(
    const int* __restrict__ src, const int* __restrict__ dst,
    const int* __restrict__ bucket_base, const int* __restrict__ cbase,
    int* __restrict__ ebuf, int nE)
{
    __shared__ int cnt[NBUCK];
    __shared__ int base[NBUCK];
    int t = threadIdx.x;
    int cid = blockIdx.x;
    for (int i = t; i < NBUCK; i += 256) {
        cnt[i] = 0;
        base[i] = bucket_base[i] + cbase[(size_t)i * NCH + cid];
    }
    __syncthreads();

    int lo = cid * CHUNK_A;
    int hi = lo + CHUNK_A;
    if (hi > nE) hi = nE;
    for (int e = lo + t; e < hi; e += 256) {
        int d = dst[e];
        int b = d >> BSHIFT;
        int p = base[b] + atomicAdd(&cnt[b], 1);
        ebuf[p] = ((d & (BSIZE - 1)) << 17) | src[e];
    }
}

__global__ __launch_bounds__(256) void bucket_build(
    const int* __restrict__ bucket_base, const int* __restrict__ ebuf,
    int* __restrict__ row_start, int* __restrict__ ssrc)
{
    int b = blockIdx.x;
    int nlo = b << BSHIFT;
    int nhi = nlo + BSIZE;
    if (nhi > N_NODES_C) nhi = N_NODES_C;
    int nloc = nhi - nlo;

    __shared__ int degl[BSIZE];
    __shared__ int posl[BSIZE];
    __shared__ int ws[4];
    int t = threadIdx.x;

    for (int i = t; i < BSIZE; i += 256) degl[i] = 0;
    __syncthreads();

    int lo = bucket_base[b];
    int hi = bucket_base[b + 1];
    for (int e = lo + t; e < hi; e += 256)
        atomicAdd(&degl[ebuf[e] >> 17], 1);
    __syncthreads();

    int base4 = t * 4;
    int v0 = degl[base4 + 0], v1 = degl[base4 + 1];
    int v2 = degl[base4 + 2], v3 = degl[base4 + 3];
    int lsum = v0 + v1 + v2 + v3;
    int incl = wave_incl_scan(lsum);
    int lane = t & 63, w = t >> 6;
    if (lane == 63) ws[w] = incl;
    __syncthreads();
    int woff = 0;
    for (int i = 0; i < w; ++i) woff += ws[i];
    int pp = lo + woff + incl - lsum;
    if (base4 + 0 < nloc) { row_start[nlo + base4 + 0] = pp; posl[base4 + 0] = pp; } pp += v0;
    if (base4 + 1 < nloc) { row_start[nlo + base4 + 1] = pp; posl[base4 + 1] = pp; } pp += v1;
    if (base4 + 2 < nloc) { row_start[nlo + base4 + 2] = pp; posl[base4 + 2] = pp; } pp += v2;
    if (base4 + 3 < nloc) { row_start[nlo + base4 + 3] = pp; posl[base4 + 3] = pp; } pp += v3;
    if (t == 0 && nhi == N_NODES_C) row_start[N_NODES_C] = hi;
    __syncthreads();

    for (int e = lo + t; e < hi; e += 256) {
        int v = ebuf[e];
        int q = atomicAdd(&posl[v >> 17], 1);
        ssrc[q] = v & 0x1FFFF;
    }
}

// ---------------------------------------------------------------------------
// Gather-sum over bf16 rows, f32 accumulation, bf16 packed output.
// ---------------------------------------------------------------------------
template<int D>
__global__ __launch_bounds__(256) void gather_bf(
    const ushort_t* __restrict__ xb, const int* __restrict__ row_start,
    const int* __restrict__ ssrc, ushort_t* __restrict__ aggb, int nNodes)
{
    const int L = D / 8;        // lanes per node
    const int NPB = 256 / L;
    int local = threadIdx.x / L;
    int lane  = threadIdx.x % L;
    int n = blockIdx.x * NPB + local;
    if (n >= nNodes) return;
    int beg = row_start[n], end = row_start[n + 1];
    float4 accA = make_float4(0.f, 0.f, 0.f, 0.f);
    float4 accB = accA;
    int e = beg;
#pragma unroll 1
    for (; e + 1 < end; e += 2) {
        int s0 = ssrc[e], s1 = ssrc[e + 1];
        uint4 u0 = reinterpret_cast<const uint4*>(xb + (size_t)s0 * D)[lane];
        uint4 u1 = reinterpret_cast<const uint4*>(xb + (size_t)s1 * D)[lane];
        accA.x += bf_lo(u0.x) + bf_lo(u1.x);
        accA.y += bf_hi(u0.x) + bf_hi(u1.x);
        accA.z += bf_lo(u0.y) + bf_lo(u1.y);
        accA.w += bf_hi(u0.y) + bf_hi(u1.y);
        accB.x += bf_lo(u0.z) + bf_lo(u1.z);
        accB.y += bf_hi(u0.z) + bf_hi(u1.z);
        accB.z += bf_lo(u0.w) + bf_lo(u1.w);
        accB.w += bf_hi(u0.w) + bf_hi(u1.w);
    }
    if (e < end) {
        int s0 = ssrc[e];
        uint4 u0 = reinterpret_cast<const uint4*>(xb + (size_t)s0 * D)[lane];
        accA.x += bf_lo(u0.x); accA.y += bf_hi(u0.x);
        accA.z += bf_lo(u0.y); accA.w += bf_hi(u0.y);
        accB.x += bf_lo(u0.z); accB.y += bf_hi(u0.z);
        accB.z += bf_lo(u0.w); accB.w += bf_hi(u0.w);
    }
    uint4 o;
    o.x = pack2bf(accA.x, accA.y); o.y = pack2bf(accA.z, accA.w);
    o.z = pack2bf(accB.x, accB.y); o.w = pack2bf(accB.z, accB.w);
    reinterpret_cast<uint4*>(aggb + (size_t)n * D)[lane] = o;
}

// ---------------------------------------------------------------------------
// MFMA node transform (round-13 measured-good, absmax-verified layouts).
// ---------------------------------------------------------------------------
template<int DIN, int DOUT>
__global__ __launch_bounds__(256) void transform_mfma(
    const ushort_t* __restrict__ aggb, const ushort_t* __restrict__ xb,
    const ushort_t* __restrict__ wcatT, const float* __restrict__ bias,
    ushort_t* __restrict__ out, int nNodes)
{
    constexpr int KT = 2 * DIN;
    constexpr int NKB = KT / 32;
    constexpr int NTILES = DOUT / 16;
    constexpr int MPB = 256;

    int wid  = threadIdx.x >> 6;
    int lane = threadIdx.x & 63;
    int l15  = lane & 15;
    int lg   = lane >> 4;

    int ntile, mstep, mofs;
    if (NTILES == 4) { ntile = wid;     mstep = 16; mofs = 0; }
    else             { ntile = wid & 1; mstep = 32; mofs = (wid >> 1) * 16; }
    int n0 = ntile * 16;

    bf16x8 bfrag[NKB];
    {
        const ushort_t* wrow = wcatT + (size_t)(n0 + l15) * KT;
#pragma unroll
        for (int kb = 0; kb < NKB; ++kb) {
            int kbase = kb * 32 + lg * 4;
            union { uint2 u[2]; bf16x8 v; } cvt;
            cvt.u[0] = *reinterpret_cast<const uint2*>(wrow + kbase);
            cvt.u[1] = *reinterpret_cast<const uint2*>(wrow + kbase + 16);
            bfrag[kb] = cvt.v;
        }
    }

    float bj = bias[n0 + l15];

    int base = blockIdx.x * MPB;
    for (int m0 = base + mofs; m0 < base + MPB; m0 += mstep) {
        int row = m0 + l15;
        bool valid_r = row < nNodes;
        f32x4 acc = {0.f, 0.f, 0.f, 0.f};
#pragma unroll
        for (int kb = 0; kb < NKB; ++kb) {
            const ushort_t* srcp = (kb < NKB / 2) ? aggb : xb;
            int kloc = (kb < NKB / 2) ? kb * 32 : kb * 32 - DIN;
            union { uint2 u[2]; bf16x8 v; } cvt;
            if (valid_r) {
                const ushort_t* arow = srcp + (size_t)row * DIN + kloc + lg * 4;
                cvt.u[0] = *reinterpret_cast<const uint2*>(arow);
                cvt.u[1] = *reinterpret_cast<const uint2*>(arow + 16);
            } else {
                cvt.u[0] = make_uint2(0, 0);
                cvt.u[1] = make_uint2(0, 0);
            }
            acc = __builtin_amdgcn_mfma_f32_16x16x32_bf16(cvt.v, bfrag[kb], acc, 0, 0, 0);
        }
#pragma unroll
        for (int r = 0; r < 4; ++r) {
            int orow = m0 + lg * 4 + r;
            if (orow < nNodes)
                out[(size_t)orow * DOUT + n0 + l15] = f2bf(elu_f(acc[r] + bj));
        }
    }
}

// ---------------------------------------------------------------------------
// Mean-pool over sorted batch, bf16 input, f32 sums.
// ---------------------------------------------------------------------------
#define POOL_CHUNK 256
__global__ __launch_bounds__(256) void pool_bf(
    const ushort_t* __restrict__ h, const int* __restrict__ batch,
    float* __restrict__ sums, float* __restrict__ cnts, int nNodes)
{
    int t = threadIdx.x;
    int j = t & 63;
    int sub = t >> 6;
    int start = blockIdx.x * POOL_CHUNK + sub;
    int end = blockIdx.x * POOL_CHUNK + POOL_CHUNK;
    if (end > nNodes) end = nNodes;
    if (start >= end) return;

    int g = batch[start];
    float acc = 0.f;
    float c = 0.f;
    for (int n = start; n < end; n += 4) {
        int gn = batch[n];
        if (gn != g) {
            unsafeAtomicAdd(&sums[(size_t)g * 64 + j], acc);
            if (j == 0) unsafeAtomicAdd(&cnts[g], c);
            acc = 0.f; c = 0.f; g = gn;
        }
        acc += __uint_as_float(((uint_t)h[(size_t)n * 64 + j]) << 16);
        c += 1.f;
    }
    unsafeAtomicAdd(&sums[(size_t)g * 64 + j], acc);
    if (j == 0) unsafeAtomicAdd(&cnts[g], c);
}

// ---------------------------------------------------------------------------
// MLP head + log_softmax: one 64-thread block per graph.
// ---------------------------------------------------------------------------
__global__ __launch_bounds__(64) void mlp_kernel(
    const float* __restrict__ sums, const float* __restrict__ cnts,
    const float* __restrict__ fw1, const float* __restrict__ fb1,
    const float* __restrict__ fw2, const float* __restrict__ fb2,
    const float* __restrict__ fw3, const float* __restrict__ fb3,
    float* __restrict__ out)
{
    int g = blockIdx.x;
    int j = threadIdx.x;
    __shared__ float p[64];
    __shared__ float z1[64];
    __shared__ float z2[32];
    __shared__ float z3[10];
    __shared__ float lse;

    float c = fmaxf(cnts[g], 1.f);
    p[j] = sums[(size_t)g * 64 + j] / c;
    __syncthreads();

    float a = fb1[j];
#pragma unroll
    for (int k = 0; k < 64; ++k) a += p[k] * fw1[k * 64 + j];
    z1[j] = elu_f(a);
    __syncthreads();

    if (j < 32) {
        float a2 = fb2[j];
#pragma unroll
        for (int k = 0; k < 64; ++k) a2 += z1[k] * fw2[k * 32 + j];
        z2[j] = elu_f(a2);
    }
    __syncthreads();

    if (j < 10) {
        float a3 = fb3[j];
#pragma unroll
        for (int k = 0; k < 32; ++k) a3 += z2[k] * fw3[k * 10 + j];
        z3[j] = a3;
    }
    __syncthreads();

    if (j == 0) {
        float m = -1e30f;
        for (int i = 0; i < 10; ++i) m = fmaxf(m, z3[i]);
        float s = 0.f;
        for (int i = 0; i < 10; ++i) s += expf(z3[i] - m);
        lse = logf(s) + m;
    }
    __syncthreads();

    if (j < 10) out[(size_t)g * 10 + j] = z3[j] - lse;
}

// ---------------------------------------------------------------------------
extern "C" void kernel_launch(void* const* d_in, const int* in_sizes, int n_in,
                              void* d_out, int out_size, void* d_ws, size_t ws_size,
                              hipStream_t stream)
{
    const float* x       = (const float*)d_in[0];
    const int*   ei      = (const int*)  d_in[1];
    const int*   batch   = (const int*)  d_in[2];
    const float* w1_rel  = (const float*)d_in[3];
    const float* b1      = (const float*)d_in[4];
    const float* w1_root = (const float*)d_in[5];
    const float* w2_rel  = (const float*)d_in[6];
    const float* b2      = (const float*)d_in[7];
    const float* w2_root = (const float*)d_in[8];
    const float* w3_rel  = (const float*)d_in[9];
    const float* b3      = (const float*)d_in[10];
    const float* w3_root = (const float*)d_in[11];
    const float* fw1     = (const float*)d_in[12];
    const float* fb1     = (const float*)d_in[13];
    const float* fw2     = (const float*)d_in[14];
    const float* fb2     = (const float*)d_in[15];
    const float* fw3     = (const float*)d_in[16];
    const float* fb3     = (const float*)d_in[17];
    float* out = (float*)d_out;

    const int* src = ei;
    const int* dst = ei + N_EDGES_C;

    // workspace layout (bf16 feature buffers)
    ushort_t* aggb = (ushort_t*)d_ws;                        // N*64 bf16 (12.8MB)
    ushort_t* xb  = aggb + (size_t)N_NODES_C * 64;           // N*32 bf16
    ushort_t* h1  = xb + (size_t)N_NODES_C * 32;             // N*32 bf16
    ushort_t* h2  = h1 + (size_t)N_NODES_C * 32;             // N*64 bf16
    ushort_t* h3  = h2 + (size_t)N_NODES_C * 64;             // N*64 bf16
    float* sums = (float*)(h3 + (size_t)N_NODES_C * 64);     // 512*64 f
    float* cnts = sums + (size_t)N_GRAPHS_C * 64;            // 512 f
    int*   row_start = (int*)(cnts + N_GRAPHS_C);            // N+1 int
    int*   btot = row_start + N_NODES_C + 1;                 // NBUCK
    int*   bucket_base = btot + NBUCK;                       // NBUCK+1
    int*   ccnt = bucket_base + NBUCK + 1;                   // NBUCK*NCH
    int*   cbase = ccnt + (size_t)NBUCK * NCH;               // NBUCK*NCH
    int*   ssrc = cbase + (size_t)NBUCK * NCH;               // nE int
    ushort_t* wc1 = (ushort_t*)((((size_t)(ssrc + N_EDGES_C)) + 15) & ~(size_t)15);
    ushort_t* wc2 = wc1 + 2048;                              // [32][64]
    ushort_t* wc3 = wc2 + 4096;                              // [64][128]
    int*   ebuf = (int*)aggb;  // aliased (12.8MB >= 6.4MB); CSR build done
                               // before layer-1 gather writes aggb

    // ---- input f32 -> bf16; weight prep ----
    cvt_bf16<<<(N_NODES_C * 32 / 8 + 255) / 256, 256, 0, stream>>>(
        x, (uint_t*)xb, N_NODES_C * 32 / 8);
    build_wcatT<<<8, 256, 0, stream>>>(w1_rel, w1_root, wc1, 32, 32);
    build_wcatT<<<16, 256, 0, stream>>>(w2_rel, w2_root, wc2, 32, 64);
    build_wcatT<<<32, 256, 0, stream>>>(w3_rel, w3_root, wc3, 64, 64);

    // ---- bucketed CSR build v2 (deterministic bases) ----
    bucket_count<<<NCH, 256, 0, stream>>>(dst, ccnt, N_EDGES_C);
    scan_chunks<<<(NBUCK + 3) / 4, 256, 0, stream>>>(ccnt, cbase, btot);
    bucket_scan<<<1, 128, 0, stream>>>(btot, bucket_base, N_EDGES_C);
    bucket_pass<<<NCH, 256, 0, stream>>>(src, dst, bucket_base, cbase, ebuf, N_EDGES_C);
    bucket_build<<<NBUCK, 256, 0, stream>>>(bucket_base, ebuf, row_start, ssrc);

    const int TB = (N_NODES_C + 255) / 256;  // transform blocks

    // ---- layer 1: 32 -> 32, xb -> h1 ----
    gather_bf<32><<<(N_NODES_C + 63) / 64, 256, 0, stream>>>(
        xb, row_start, ssrc, aggb, N_NODES_C);
    transform_mfma<32, 32><<<TB, 256, 0, stream>>>(
        aggb, xb, wc1, b1, h1, N_NODES_C);

    // ---- layer 2: 32 -> 64, h1 -> h2 ----
    gather_bf<32><<<(N_NODES_C + 63) / 64, 256, 0, stream>>>(
        h1, row_start, ssrc, aggb, N_NODES_C);
    transform_mfma<32, 64><<<TB, 256, 0, stream>>>(
        aggb, h1, wc2, b2, h2, N_NODES_C);

    // ---- layer 3: 64 -> 64, h2 -> h3 ----
    gather_bf<64><<<(N_NODES_C + 31) / 32, 256, 0, stream>>>(
        h2, row_start, ssrc, aggb, N_NODES_C);
    transform_mfma<64, 64><<<TB, 256, 0, stream>>>(
        aggb, h2, wc3, b3, h3, N_NODES_C);

    // ---- mean pool ----
    hipMemsetAsync(sums, 0, ((size_t)N_GRAPHS_C * 64 + N_GRAPHS_C) * sizeof(float), stream);
    pool_bf<<<(N_NODES_C + POOL_CHUNK - 1) / POOL_CHUNK, 256, 0, stream>>>(
        h3, batch, sums, cnts, N_NODES_C);

    // ---- MLP head + log_softmax ----
    mlp_kernel<<<N_GRAPHS_C, 64, 0, stream>>>(
        sums, cnts, fw1, fb1, fw2, fb2, fw3, fb3, out);
}

// Round 15
// 243.300 us; speedup vs baseline: 1.2331x; 1.0305x over previous
//
#include <hip/hip_runtime.h>
#include <hip/hip_bf16.h>
#include <math.h>

#define N_NODES_C 100000
#define N_EDGES_C 1600000
#define N_GRAPHS_C 512
#define BSHIFT 7
#define BSIZE (1 << BSHIFT)
#define NBUCK ((N_NODES_C + BSIZE - 1) >> BSHIFT)   // 782
#define CHUNK_A 2048
#define NCH ((N_EDGES_C + CHUNK_A - 1) / CHUNK_A)   // 782

typedef unsigned int  uint_t;
typedef unsigned short ushort_t;
typedef __attribute__((ext_vector_type(8))) short bf16x8;
typedef __attribute__((ext_vector_type(4))) float f32x4;

__device__ __forceinline__ float elu_f(float x) { return x > 0.f ? x : expm1f(x); }

// bf16 helpers (RNE pack, shift unpack). Finite values only.
__device__ __forceinline__ ushort_t f2bf(float f) {
    uint_t u = __float_as_uint(f);
    u += 0x7FFFu + ((u >> 16) & 1u);
    return (ushort_t)(u >> 16);
}
__device__ __forceinline__ uint_t pack2bf(float lo, float hi) {
    return (uint_t)f2bf(lo) | ((uint_t)f2bf(hi) << 16);
}
__device__ __forceinline__ float bf_lo(uint_t u) { return __uint_as_float(u << 16); }
__device__ __forceinline__ float bf_hi(uint_t u) { return __uint_as_float(u & 0xFFFF0000u); }

__device__ __forceinline__ int wave_incl_scan(int v) {
    int lane = threadIdx.x & 63;
#pragma unroll
    for (int o = 1; o < 64; o <<= 1) {
        int t = __shfl_up(v, o);
        if (lane >= o) v += t;
    }
    return v;
}

// ---------------------------------------------------------------------------
// f32 -> bf16 conversion of the input features (8 elems/thread).
// ---------------------------------------------------------------------------
__global__ __launch_bounds__(256) void cvt_bf16(
    const float* __restrict__ in, uint_t* __restrict__ out, int n8)
{
    int i = blockIdx.x * 256 + threadIdx.x;
    if (i >= n8) return;
    const float4* p = reinterpret_cast<const float4*>(in) + 2 * i;
    float4 a = p[0], b = p[1];
    uint4 o;
    o.x = pack2bf(a.x, a.y); o.y = pack2bf(a.z, a.w);
    o.z = pack2bf(b.x, b.y); o.w = pack2bf(b.z, b.w);
    reinterpret_cast<uint4*>(out)[i] = o;
}

// ---------------------------------------------------------------------------
// Build transposed+concatenated bf16 weights for the MFMA transform.
// ---------------------------------------------------------------------------
__global__ __launch_bounds__(256) void build_wcatT(
    const float* __restrict__ wr, const float* __restrict__ wt,
    ushort_t* __restrict__ o, int DIN, int DOUT)
{
    int idx = blockIdx.x * 256 + threadIdx.x;
    int KT = 2 * DIN;
    if (idx >= DOUT * KT) return;
    int n = idx / KT, k = idx % KT;
    float v = (k < DIN) ? wr[k * DOUT + n] : wt[(k - DIN) * DOUT + n];
    o[idx] = f2bf(v);
}

// ---------------------------------------------------------------------------
// Bucketed CSR build v3: 128-node buckets (782 blocks ~ 3/CU; v2's 98-block
// bucket_build sat at 3.3% occupancy). Deterministic per-chunk bases.
// ebuf packed: (local_dst:7b << 17) | src:17b.
// ---------------------------------------------------------------------------
__global__ __launch_bounds__(256) void bucket_count(
    const int* __restrict__ dst, int* __restrict__ ccnt, int nE)
{
    __shared__ int cnt[NBUCK];
    int t = threadIdx.x;
    for (int i = t; i < NBUCK; i += 256) cnt[i] = 0;
    __syncthreads();
    int lo = blockIdx.x * CHUNK_A;
    int hi = lo + CHUNK_A;
    if (hi > nE) hi = nE;
    for (int e = lo + t; e < hi; e += 256)
        atomicAdd(&cnt[dst[e] >> BSHIFT], 1);
    __syncthreads();
    for (int i = t; i < NBUCK; i += 256)
        ccnt[(size_t)i * NCH + blockIdx.x] = cnt[i];
}

__global__ __launch_bounds__(256) void scan_chunks(
    const int* __restrict__ ccnt, int* __restrict__ cbase, int* __restrict__ btot)
{
    int wid = blockIdx.x * 4 + (threadIdx.x >> 6);  // bucket
    int lane = threadIdx.x & 63;
    if (wid >= NBUCK) return;
    const int* row = ccnt + (size_t)wid * NCH;
    int* orow = cbase + (size_t)wid * NCH;
    int running = 0;
    for (int c0 = 0; c0 < NCH; c0 += 64) {
        int c = c0 + lane;
        int v = (c < NCH) ? row[c] : 0;
        int incl = wave_incl_scan(v);
        if (c < NCH) orow[c] = running + incl - v;
        running += __shfl(incl, 63);
    }
    if (lane == 0) btot[wid] = running;
}

__global__ __launch_bounds__(1024) void bucket_scan(
    const int* __restrict__ btot, int* __restrict__ bucket_base, int nE)
{
    int tid = threadIdx.x;  // NBUCK <= 1024
    int v = tid < NBUCK ? btot[tid] : 0;
    int lane = tid & 63, w = tid >> 6;  // 16 waves
    int incl = wave_incl_scan(v);
    __shared__ int ws[16];
    if (lane == 63) ws[w] = incl;
    __syncthreads();
    int woff = 0;
    for (int i = 0; i < w; ++i) woff += ws[i];
    if (tid < NBUCK) bucket_base[tid] = woff + incl - v;
    if (tid == 0) bucket_base[NBUCK] = nE;
}

__global__ __launch_bounds__(256) void bucket_pass(
    const int* __restrict__ src, const int* __restrict__ dst,
    const int* __restrict__ bucket_base, const int* __restrict__ cbase,
    int* __restrict__ ebuf, int nE)
{
    __shared__ int cnt[NBUCK];
    __shared__ int base[NBUCK];
    int t = threadIdx.x;
    int cid = blockIdx.x;
    for (int i = t; i < NBUCK; i += 256) {
        cnt[i] = 0;
        base[i] = bucket_base[i] + cbase[(size_t)i * NCH + cid];
    }
    __syncthreads();

    int lo = cid * CHUNK_A;
    int hi = lo + CHUNK_A;
    if (hi > nE) hi = nE;
    for (int e = lo + t; e < hi; e += 256) {
        int d = dst[e];
        int b = d >> BSHIFT;
        int p = base[b] + atomicAdd(&cnt[b], 1);
        ebuf[p] = ((d & (BSIZE - 1)) << 17) | src[e];
    }
}

__global__ __launch_bounds__(256) void bucket_build(
    const int* __restrict__ bucket_base, const int* __restrict__ ebuf,
    int* __restrict__ row_start, int* __restrict__ ssrc)
{
    int b = blockIdx.x;
    int nlo = b << BSHIFT;
    int nhi = nlo + BSIZE;
    if (nhi > N_NODES_C) nhi = N_NODES_C;
    int nloc = nhi - nlo;

    __shared__ int degl[BSIZE];
    __shared__ int posl[BSIZE];
    __shared__ int ws[4];
    int t = threadIdx.x;

    if (t < BSIZE) degl[t] = 0;
    __syncthreads();

    int lo = bucket_base[b];
    int hi = bucket_base[b + 1];
    for (int e = lo + t; e < hi; e += 256)
        atomicAdd(&degl[ebuf[e] >> 17], 1);
    __syncthreads();

    // exclusive scan over BSIZE=128 elems using all 256 threads (v=0 beyond)
    int v = (t < nloc) ? degl[t] : 0;
    int incl = wave_incl_scan(v);
    int lane = t & 63, w = t >> 6;
    if (lane == 63) ws[w] = incl;
    __syncthreads();
    int woff = 0;
    for (int i = 0; i < w; ++i) woff += ws[i];
    int pp = lo + woff + incl - v;
    if (t < nloc) { row_start[nlo + t] = pp; posl[t] = pp; }
    if (t == 0 && nhi == N_NODES_C) row_start[N_NODES_C] = hi;
    __syncthreads();

    for (int e = lo + t; e < hi; e += 256) {
        int x = ebuf[e];
        int q = atomicAdd(&posl[x >> 17], 1);
        ssrc[q] = x & 0x1FFFF;
    }
}

// ---------------------------------------------------------------------------
// Gather-sum over bf16 rows, f32 accumulation, bf16 packed output.
// ---------------------------------------------------------------------------
template<int D>
__global__ __launch_bounds__(256) void gather_bf(
    const ushort_t* __restrict__ xb, const int* __restrict__ row_start,
    const int* __restrict__ ssrc, ushort_t* __restrict__ aggb, int nNodes)
{
    const int L = D / 8;        // lanes per node
    const int NPB = 256 / L;
    int local = threadIdx.x / L;
    int lane  = threadIdx.x % L;
    int n = blockIdx.x * NPB + local;
    if (n >= nNodes) return;
    int beg = row_start[n], end = row_start[n + 1];
    float4 accA = make_float4(0.f, 0.f, 0.f, 0.f);
    float4 accB = accA;
    int e = beg;
#pragma unroll 1
    for (; e + 1 < end; e += 2) {
        int s0 = ssrc[e], s1 = ssrc[e + 1];
        uint4 u0 = reinterpret_cast<const uint4*>(xb + (size_t)s0 * D)[lane];
        uint4 u1 = reinterpret_cast<const uint4*>(xb + (size_t)s1 * D)[lane];
        accA.x += bf_lo(u0.x) + bf_lo(u1.x);
        accA.y += bf_hi(u0.x) + bf_hi(u1.x);
        accA.z += bf_lo(u0.y) + bf_lo(u1.y);
        accA.w += bf_hi(u0.y) + bf_hi(u1.y);
        accB.x += bf_lo(u0.z) + bf_lo(u1.z);
        accB.y += bf_hi(u0.z) + bf_hi(u1.z);
        accB.z += bf_lo(u0.w) + bf_lo(u1.w);
        accB.w += bf_hi(u0.w) + bf_hi(u1.w);
    }
    if (e < end) {
        int s0 = ssrc[e];
        uint4 u0 = reinterpret_cast<const uint4*>(xb + (size_t)s0 * D)[lane];
        accA.x += bf_lo(u0.x); accA.y += bf_hi(u0.x);
        accA.z += bf_lo(u0.y); accA.w += bf_hi(u0.y);
        accB.x += bf_lo(u0.z); accB.y += bf_hi(u0.z);
        accB.z += bf_lo(u0.w); accB.w += bf_hi(u0.w);
    }
    uint4 o;
    o.x = pack2bf(accA.x, accA.y); o.y = pack2bf(accA.z, accA.w);
    o.z = pack2bf(accB.x, accB.y); o.w = pack2bf(accB.z, accB.w);
    reinterpret_cast<uint4*>(aggb + (size_t)n * D)[lane] = o;
}

// ---------------------------------------------------------------------------
// MFMA node transform (round-13 measured-good, absmax-verified layouts).
// ---------------------------------------------------------------------------
template<int DIN, int DOUT>
__global__ __launch_bounds__(256) void transform_mfma(
    const ushort_t* __restrict__ aggb, const ushort_t* __restrict__ xb,
    const ushort_t* __restrict__ wcatT, const float* __restrict__ bias,
    ushort_t* __restrict__ out, int nNodes)
{
    constexpr int KT = 2 * DIN;
    constexpr int NKB = KT / 32;
    constexpr int NTILES = DOUT / 16;
    constexpr int MPB = 256;

    int wid  = threadIdx.x >> 6;
    int lane = threadIdx.x & 63;
    int l15  = lane & 15;
    int lg   = lane >> 4;

    int ntile, mstep, mofs;
    if (NTILES == 4) { ntile = wid;     mstep = 16; mofs = 0; }
    else             { ntile = wid & 1; mstep = 32; mofs = (wid >> 1) * 16; }
    int n0 = ntile * 16;

    bf16x8 bfrag[NKB];
    {
        const ushort_t* wrow = wcatT + (size_t)(n0 + l15) * KT;
#pragma unroll
        for (int kb = 0; kb < NKB; ++kb) {
            int kbase = kb * 32 + lg * 4;
            union { uint2 u[2]; bf16x8 v; } cvt;
            cvt.u[0] = *reinterpret_cast<const uint2*>(wrow + kbase);
            cvt.u[1] = *reinterpret_cast<const uint2*>(wrow + kbase + 16);
            bfrag[kb] = cvt.v;
        }
    }

    float bj = bias[n0 + l15];

    int base = blockIdx.x * MPB;
    for (int m0 = base + mofs; m0 < base + MPB; m0 += mstep) {
        int row = m0 + l15;
        bool valid_r = row < nNodes;
        f32x4 acc = {0.f, 0.f, 0.f, 0.f};
#pragma unroll
        for (int kb = 0; kb < NKB; ++kb) {
            const ushort_t* srcp = (kb < NKB / 2) ? aggb : xb;
            int kloc = (kb < NKB / 2) ? kb * 32 : kb * 32 - DIN;
            union { uint2 u[2]; bf16x8 v; } cvt;
            if (valid_r) {
                const ushort_t* arow = srcp + (size_t)row * DIN + kloc + lg * 4;
                cvt.u[0] = *reinterpret_cast<const uint2*>(arow);
                cvt.u[1] = *reinterpret_cast<const uint2*>(arow + 16);
            } else {
                cvt.u[0] = make_uint2(0, 0);
                cvt.u[1] = make_uint2(0, 0);
            }
            acc = __builtin_amdgcn_mfma_f32_16x16x32_bf16(cvt.v, bfrag[kb], acc, 0, 0, 0);
        }
#pragma unroll
        for (int r = 0; r < 4; ++r) {
            int orow = m0 + lg * 4 + r;
            if (orow < nNodes)
                out[(size_t)orow * DOUT + n0 + l15] = f2bf(elu_f(acc[r] + bj));
        }
    }
}

// ---------------------------------------------------------------------------
// Mean-pool over sorted batch, bf16 input, f32 sums.
// ---------------------------------------------------------------------------
#define POOL_CHUNK 256
__global__ __launch_bounds__(256) void pool_bf(
    const ushort_t* __restrict__ h, const int* __restrict__ batch,
    float* __restrict__ sums, float* __restrict__ cnts, int nNodes)
{
    int t = threadIdx.x;
    int j = t & 63;
    int sub = t >> 6;
    int start = blockIdx.x * POOL_CHUNK + sub;
    int end = blockIdx.x * POOL_CHUNK + POOL_CHUNK;
    if (end > nNodes) end = nNodes;
    if (start >= end) return;

    int g = batch[start];
    float acc = 0.f;
    float c = 0.f;
    for (int n = start; n < end; n += 4) {
        int gn = batch[n];
        if (gn != g) {
            unsafeAtomicAdd(&sums[(size_t)g * 64 + j], acc);
            if (j == 0) unsafeAtomicAdd(&cnts[g], c);
            acc = 0.f; c = 0.f; g = gn;
        }
        acc += __uint_as_float(((uint_t)h[(size_t)n * 64 + j]) << 16);
        c += 1.f;
    }
    unsafeAtomicAdd(&sums[(size_t)g * 64 + j], acc);
    if (j == 0) unsafeAtomicAdd(&cnts[g], c);
}

// ---------------------------------------------------------------------------
// MLP head + log_softmax: one 64-thread block per graph.
// ---------------------------------------------------------------------------
__global__ __launch_bounds__(64) void mlp_kernel(
    const float* __restrict__ sums, const float* __restrict__ cnts,
    const float* __restrict__ fw1, const float* __restrict__ fb1,
    const float* __restrict__ fw2, const float* __restrict__ fb2,
    const float* __restrict__ fw3, const float* __restrict__ fb3,
    float* __restrict__ out)
{
    int g = blockIdx.x;
    int j = threadIdx.x;
    __shared__ float p[64];
    __shared__ float z1[64];
    __shared__ float z2[32];
    __shared__ float z3[10];
    __shared__ float lse;

    float c = fmaxf(cnts[g], 1.f);
    p[j] = sums[(size_t)g * 64 + j] / c;
    __syncthreads();

    float a = fb1[j];
#pragma unroll
    for (int k = 0; k < 64; ++k) a += p[k] * fw1[k * 64 + j];
    z1[j] = elu_f(a);
    __syncthreads();

    if (j < 32) {
        float a2 = fb2[j];
#pragma unroll
        for (int k = 0; k < 64; ++k) a2 += z1[k] * fw2[k * 32 + j];
        z2[j] = elu_f(a2);
    }
    __syncthreads();

    if (j < 10) {
        float a3 = fb3[j];
#pragma unroll
        for (int k = 0; k < 32; ++k) a3 += z2[k] * fw3[k * 10 + j];
        z3[j] = a3;
    }
    __syncthreads();

    if (j == 0) {
        float m = -1e30f;
        for (int i = 0; i < 10; ++i) m = fmaxf(m, z3[i]);
        float s = 0.f;
        for (int i = 0; i < 10; ++i) s += expf(z3[i] - m);
        lse = logf(s) + m;
    }
    __syncthreads();

    if (j < 10) out[(size_t)g * 10 + j] = z3[j] - lse;
}

// ---------------------------------------------------------------------------
extern "C" void kernel_launch(void* const* d_in, const int* in_sizes, int n_in,
                              void* d_out, int out_size, void* d_ws, size_t ws_size,
                              hipStream_t stream)
{
    const float* x       = (const float*)d_in[0];
    const int*   ei      = (const int*)  d_in[1];
    const int*   batch   = (const int*)  d_in[2];
    const float* w1_rel  = (const float*)d_in[3];
    const float* b1      = (const float*)d_in[4];
    const float* w1_root = (const float*)d_in[5];
    const float* w2_rel  = (const float*)d_in[6];
    const float* b2      = (const float*)d_in[7];
    const float* w2_root = (const float*)d_in[8];
    const float* w3_rel  = (const float*)d_in[9];
    const float* b3      = (const float*)d_in[10];
    const float* w3_root = (const float*)d_in[11];
    const float* fw1     = (const float*)d_in[12];
    const float* fb1     = (const float*)d_in[13];
    const float* fw2     = (const float*)d_in[14];
    const float* fb2     = (const float*)d_in[15];
    const float* fw3     = (const float*)d_in[16];
    const float* fb3     = (const float*)d_in[17];
    float* out = (float*)d_out;

    const int* src = ei;
    const int* dst = ei + N_EDGES_C;

    // workspace layout (bf16 feature buffers)
    ushort_t* aggb = (ushort_t*)d_ws;                        // N*64 bf16 (12.8MB)
    ushort_t* xb  = aggb + (size_t)N_NODES_C * 64;           // N*32 bf16
    ushort_t* h1  = xb + (size_t)N_NODES_C * 32;             // N*32 bf16
    ushort_t* h2  = h1 + (size_t)N_NODES_C * 32;             // N*64 bf16
    ushort_t* h3  = h2 + (size_t)N_NODES_C * 64;             // N*64 bf16
    float* sums = (float*)(h3 + (size_t)N_NODES_C * 64);     // 512*64 f
    float* cnts = sums + (size_t)N_GRAPHS_C * 64;            // 512 f
    int*   row_start = (int*)(cnts + N_GRAPHS_C);            // N+1 int
    int*   btot = row_start + N_NODES_C + 1;                 // NBUCK
    int*   bucket_base = btot + NBUCK;                       // NBUCK+1
    int*   ccnt = bucket_base + NBUCK + 1;                   // NBUCK*NCH (2.4MB)
    int*   cbase = ccnt + (size_t)NBUCK * NCH;               // NBUCK*NCH (2.4MB)
    int*   ssrc = cbase + (size_t)NBUCK * NCH;               // nE int
    ushort_t* wc1 = (ushort_t*)((((size_t)(ssrc + N_EDGES_C)) + 15) & ~(size_t)15);
    ushort_t* wc2 = wc1 + 2048;                              // [32][64]
    ushort_t* wc3 = wc2 + 4096;                              // [64][128]
    int*   ebuf = (int*)aggb;  // aliased (12.8MB >= 6.4MB); CSR build done
                               // before layer-1 gather writes aggb

    // ---- input f32 -> bf16; weight prep ----
    cvt_bf16<<<(N_NODES_C * 32 / 8 + 255) / 256, 256, 0, stream>>>(
        x, (uint_t*)xb, N_NODES_C * 32 / 8);
    build_wcatT<<<8, 256, 0, stream>>>(w1_rel, w1_root, wc1, 32, 32);
    build_wcatT<<<16, 256, 0, stream>>>(w2_rel, w2_root, wc2, 32, 64);
    build_wcatT<<<32, 256, 0, stream>>>(w3_rel, w3_root, wc3, 64, 64);

    // ---- bucketed CSR build v3 (128-node buckets) ----
    bucket_count<<<NCH, 256, 0, stream>>>(dst, ccnt, N_EDGES_C);
    scan_chunks<<<(NBUCK + 3) / 4, 256, 0, stream>>>(ccnt, cbase, btot);
    bucket_scan<<<1, 1024, 0, stream>>>(btot, bucket_base, N_EDGES_C);
    bucket_pass<<<NCH, 256, 0, stream>>>(src, dst, bucket_base, cbase, ebuf, N_EDGES_C);
    bucket_build<<<NBUCK, 256, 0, stream>>>(bucket_base, ebuf, row_start, ssrc);

    const int TB = (N_NODES_C + 255) / 256;  // transform blocks

    // ---- layer 1: 32 -> 32, xb -> h1 ----
    gather_bf<32><<<(N_NODES_C + 63) / 64, 256, 0, stream>>>(
        xb, row_start, ssrc, aggb, N_NODES_C);
    transform_mfma<32, 32><<<TB, 256, 0, stream>>>(
        aggb, xb, wc1, b1, h1, N_NODES_C);

    // ---- layer 2: 32 -> 64, h1 -> h2 ----
    gather_bf<32><<<(N_NODES_C + 63) / 64, 256, 0, stream>>>(
        h1, row_start, ssrc, aggb, N_NODES_C);
    transform_mfma<32, 64><<<TB, 256, 0, stream>>>(
        aggb, h1, wc2, b2, h2, N_NODES_C);

    // ---- layer 3: 64 -> 64, h2 -> h3 ----
    gather_bf<64><<<(N_NODES_C + 31) / 32, 256, 0, stream>>>(
        h2, row_start, ssrc, aggb, N_NODES_C);
    transform_mfma<64, 64><<<TB, 256, 0, stream>>>(
        aggb, h2, wc3, b3, h3, N_NODES_C);

    // ---- mean pool ----
    hipMemsetAsync(sums, 0, ((size_t)N_GRAPHS_C * 64 + N_GRAPHS_C) * sizeof(float), stream);
    pool_bf<<<(N_NODES_C + POOL_CHUNK - 1) / POOL_CHUNK, 256, 0, stream>>>(
        h3, batch, sums, cnts, N_NODES_C);

    // ---- MLP head + log_softmax ----
    mlp_kernel<<<N_GRAPHS_C, 64, 0, stream>>>(
        sums, cnts, fw1, fb1, fw2, fb2, fw3, fb3, out);
}